// Round 1
// 994.747 us; speedup vs baseline: 1.0065x; 1.0065x over previous
//
#include <hip/hip_runtime.h>
#include <hip/hip_bf16.h>
#include <stdint.h>

#define Bn 256
#define Tn 512
#define Hn 128
#define G4 512   // 4*H
#define Mn (Bn*Tn)

typedef __attribute__((ext_vector_type(8))) short s16x8;
typedef __attribute__((ext_vector_type(4))) float f32x4;

__device__ __forceinline__ float b2f(unsigned short u) {
    union { unsigned int i; float f; } v; v.i = ((unsigned int)u) << 16; return v.f;
}
__device__ __forceinline__ unsigned short f2b(float f) {
    union { float f; unsigned int i; } v; v.f = f;
    unsigned int x = v.i;
    unsigned int r = (x + 0x7FFFu + ((x >> 16) & 1u)) >> 16;
    return (unsigned short)r;
}
// packed fp32x2 -> bf16x2 (RNE)
__device__ __forceinline__ unsigned int pk2(float a, float b) {
    __hip_bfloat162 t = __float22bfloat162_rn(make_float2(a, b));
    union { __hip_bfloat162 v; unsigned int u; } c; c.v = t; return c.u;
}
// 8 consecutive fp32 -> bf16 fragment (used by rec for W_hh, once per block)
__device__ __forceinline__ s16x8 cvt8v(const float* p) {
    f32x4 a = *(const f32x4*)p;
    f32x4 b = *(const f32x4*)(p + 4);
    s16x8 r;
    r[0] = (short)f2b(a[0]); r[1] = (short)f2b(a[1]);
    r[2] = (short)f2b(a[2]); r[3] = (short)f2b(a[3]);
    r[4] = (short)f2b(b[0]); r[5] = (short)f2b(b[1]);
    r[6] = (short)f2b(b[2]); r[7] = (short)f2b(b[3]);
    return r;
}
__device__ __forceinline__ float sigm(float x) {
    return __builtin_amdgcn_rcpf(1.f + __expf(-x));
}
__device__ __forceinline__ float tanh_f(float x) {
    return 1.f - 2.f * __builtin_amdgcn_rcpf(1.f + __expf(2.f * x));
}
__device__ __forceinline__ void gload16(const void* gsrc, void* lds) {
    __builtin_amdgcn_global_load_lds(
        (const __attribute__((address_space(1))) unsigned int*)gsrc,
        (__attribute__((address_space(3))) unsigned int*)lds, 16, 0, 0);
}
// LDS-only barrier: waits DS ops but NOT outstanding global loads/stores.
// Safe when inter-wave communication is exclusively through LDS.
__device__ __forceinline__ void ldsbar() {
    asm volatile("s_waitcnt lgkmcnt(0)\n\ts_barrier" ::: "memory");
}

// ---------------------------------------------------------------------------
// prep: fp32 -> bf16 conversions into d_out scratch (y1 region, written last)
// ---------------------------------------------------------------------------
__global__ __launch_bounds__(256)
void prep(const float* __restrict__ x,
          const float* __restrict__ w0f, const float* __restrict__ w0b,
          const float* __restrict__ w1f, const float* __restrict__ w1b,
          unsigned short* __restrict__ xb,
          unsigned short* __restrict__ w0bf,
          unsigned short* __restrict__ w1bf)
{
    int tid = blockIdx.x * 256 + threadIdx.x;
    int nthr = gridDim.x * 256;
    for (int idx = tid; idx < Mn * 32; idx += nthr) {
        int row = idx >> 5, col = idx & 31;
        xb[idx] = f2b(col < 24 ? x[row * 24 + col] : 0.f);
    }
    for (int idx = tid; idx < 2 * 512 * 32; idx += nthr) {
        int d = idx >> 14, rem = idx & 16383;
        int n = rem >> 5, col = rem & 31;
        const float* w = d ? w0b : w0f;
        w0bf[idx] = f2b(col < 24 ? w[n * 24 + col] : 0.f);
    }
    for (int idx = tid; idx < 2 * 512 * 256; idx += nthr) {
        int d = idx >> 17, rem = idx & 131071;
        const float* w = d ? w1b : w1f;
        w1bf[idx] = f2b(w[rem]);
    }
}

// ---------------------------------------------------------------------------
// Tiled GEMM (unchanged, passing): gx[dir][m][n] = A@W^T, bf16.
// ---------------------------------------------------------------------------
template<int BK, int KOUT>
__global__ __launch_bounds__(256, 2)
void gemm_tile(const unsigned short* __restrict__ A, int lda,
               const unsigned short* __restrict__ W,   // [2][512][BK*KOUT]
               unsigned short* __restrict__ gx)
{
    constexpr int GR = BK / 8;
    constexpr int SWM = (GR >= 8) ? 7 : (GR - 1);
    constexpr int ASZ = 128 * BK * 2;
    constexpr int GOFF = (BK == 128) ? 0 : 2 * ASZ;
    constexpr int SMEM = 2 * ASZ + ((BK == 128) ? 0 : 4 * 16 * 68 * 4);
    __shared__ char smem[SMEM];
    unsigned short* Atile = (unsigned short*)smem;
    unsigned short* Btile = (unsigned short*)(smem + ASZ);

    const int K = BK * KOUT;
    const int mb = blockIdx.x;
    const int nb = blockIdx.y;
    const int dir = nb >> 2, ncol0 = (nb & 3) * 128;
    const int row0 = mb * 128;
    const unsigned short* Asrc = A + (size_t)row0 * lda;
    const unsigned short* Bsrc = W + (size_t)dir * 512 * K + (size_t)ncol0 * K;
    unsigned short* out = gx + (size_t)dir * Mn * G4;

    const int tid = threadIdx.x;
    const int w = tid >> 6, l = tid & 63;
    const int q = l >> 4, i = l & 15;
    const int wm = w >> 1, wn = w & 1;

    f32x4 acc[4][4];
#pragma unroll
    for (int a = 0; a < 4; ++a)
#pragma unroll
        for (int b = 0; b < 4; ++b) acc[a][b] = f32x4{0.f, 0.f, 0.f, 0.f};

    for (int ko = 0; ko < KOUT; ++ko) {
#pragma unroll
        for (int it = 0; it < (128 * GR) / 256; ++it) {
            int g = it * 256 + tid;
            int row = g / GR, p = g % GR;
            int gi = p ^ (row & SWM);
            gload16(Asrc + (size_t)row * lda + ko * BK + gi * 8,
                    (char*)Atile + g * 16);
        }
#pragma unroll
        for (int it = 0; it < (128 * GR) / 256; ++it) {
            int g = it * 256 + tid;
            int row = g / GR, p = g % GR;
            int gi = p ^ (row & SWM);
            gload16(Bsrc + (size_t)row * K + ko * BK + gi * 8,
                    (char*)Btile + g * 16);
        }
        __syncthreads();   // must drain vmcnt (global_load_lds) — keep full sync
#pragma unroll
        for (int kf = 0; kf < BK / 32; ++kf) {
            s16x8 af[4], bf[4];
#pragma unroll
            for (int mt = 0; mt < 4; ++mt) {
                int ar = wm * 64 + mt * 16 + i;
                int p = (kf * 4 + q) ^ (ar & SWM);
                af[mt] = *(const s16x8*)((char*)Atile + (ar * GR + p) * 16);
            }
#pragma unroll
            for (int nt = 0; nt < 4; ++nt) {
                int br = wn * 64 + nt * 16 + i;
                int p = (kf * 4 + q) ^ (br & SWM);
                bf[nt] = *(const s16x8*)((char*)Btile + (br * GR + p) * 16);
            }
#pragma unroll
            for (int mt = 0; mt < 4; ++mt)
#pragma unroll
                for (int nt = 0; nt < 4; ++nt)
                    acc[mt][nt] = __builtin_amdgcn_mfma_f32_16x16x32_bf16(
                        af[mt], bf[nt], acc[mt][nt], 0, 0, 0);
        }
        __syncthreads();
    }

    float* gbufw = (float*)(smem + GOFF) + w * (16 * 68);
#pragma unroll
    for (int mt = 0; mt < 4; ++mt) {
#pragma unroll
        for (int nt = 0; nt < 4; ++nt)
#pragma unroll
            for (int r = 0; r < 4; ++r)
                gbufw[(q * 4 + r) * 68 + nt * 16 + i] = acc[mt][nt][r];
        __syncthreads();
#pragma unroll
        for (int it2 = 0; it2 < 2; ++it2) {
            int rr = (l >> 3) + it2 * 8;
            int cc = (l & 7) * 8;
            const float* gsrc = gbufw + rr * 68 + cc;
            uint4 pv;
            pv.x = pk2(gsrc[0], gsrc[1]);
            pv.y = pk2(gsrc[2], gsrc[3]);
            pv.z = pk2(gsrc[4], gsrc[5]);
            pv.w = pk2(gsrc[6], gsrc[7]);
            *(uint4*)(out + (size_t)(row0 + wm * 64 + mt * 16 + rr) * G4
                          + ncol0 + wn * 64 + cc) = pv;
        }
        __syncthreads();
    }
}

// ---------------------------------------------------------------------------
// Recurrent sweep v3:
//  - MFMA issue order kf-outer / nt-inner: consecutive issues hit 8
//    independent accumulator chains (was 4-deep dependent back-to-back).
//  - Gs transposed to [m][n] planes: elementwise reads/writes are stride-1
//    dwords (was stride-8B -> 4 lanes/bank on the critical tail).
//  - gx+bias pre-combined BEFORE barrier 1 (off the critical tail; vmcnt
//    wait for the 8-step-ahead prefetch overlaps the MFMA phase).
//  - h fp32->bf16 via single v_cvt_pk_bf16_f32 (was 5-op manual RNE on the
//    serial chain).
//  - All LDS addresses hoisted; global gx/y addressing strength-reduced to
//    running pointers (+-const per step).
//  - LAYER templated: no per-step uniform branch, dead store-pointer DCE'd.
// ---------------------------------------------------------------------------
template<int LAYER>
__global__ __launch_bounds__(256, 1)
void lstm_rec(const unsigned short* __restrict__ gx,
              const float* __restrict__ Whf,
              const float* __restrict__ Whb,
              const float* __restrict__ biasf,
              const float* __restrict__ biasb,
              float* __restrict__ y,
              unsigned short* __restrict__ y0b,
              float* __restrict__ hn,
              float* __restrict__ cn)
{
    const int b0  = blockIdx.x * 2;
    const int dir = blockIdx.y;
    const float* Wh   = dir ? Whb : Whf;
    const float* bias = dir ? biasb : biasf;
    const unsigned short* gxd = gx + (size_t)dir * Mn * G4;

    const int tid = threadIdx.x;
    const int w = tid >> 6, l = tid & 63;
    const int q = l >> 4, i = l & 15;

    __shared__ unsigned short hbuf[16][136];
    __shared__ float Gs[2][512];   // [batch-in-pair][gate-n] : stride-1 access

    for (int idx = tid; idx < 16 * 136; idx += 256)
        ((unsigned short*)hbuf)[idx] = 0;

    s16x8 wh[8][4];
#pragma unroll
    for (int nt = 0; nt < 8; ++nt) {
        int n = w * 128 + nt * 16 + i;
#pragma unroll
        for (int kf = 0; kf < 4; ++kf)
            wh[nt][kf] = cvt8v(Wh + (size_t)n * Hn + kf * 32 + q * 8);
    }

    const int m = tid >> 7;
    const int j = tid & 127;
    const int b = b0 + m;
    const float bi = bias[j],       bfv = bias[128 + j];
    const float bg = bias[256 + j], bo  = bias[384 + j];
    float c = 0.f, hlast = 0.f;

    // hoisted LDS pointers (loop-invariant)
    const s16x8* ah0p = (const s16x8*)&hbuf[i][0 * 32 + q * 8];
    const s16x8* ah1p = (const s16x8*)&hbuf[i][1 * 32 + q * 8];
    const s16x8* ah2p = (const s16x8*)&hbuf[i][2 * 32 + q * 8];
    const s16x8* ah3p = (const s16x8*)&hbuf[i][3 * 32 + q * 8];
    float* gw0 = &Gs[0][w * 128 + i];      // q==0 lanes write gw0[nt*16]
    float* gw1 = &Gs[1][w * 128 + i];
    const float* gr = &Gs[m][j];           // reads gr[0/128/256/384], stride-1
    unsigned short* hw = &hbuf[m][j];

    // strength-reduced global pointers
    const intptr_t gstep = dir ? -(intptr_t)G4 : (intptr_t)G4;
    const unsigned short* p0 =
        gxd + ((size_t)b * Tn + (dir ? Tn - 1 : 0)) * G4 + j;
    const unsigned short* gp_pre = p0 + 8 * gstep;   // addr of logical step 8
    const intptr_t ystep = dir ? (intptr_t)-256 : (intptr_t)256;
    float* yp = y + ((size_t)b * Tn + (dir ? Tn - 1 : 0)) * 256 + dir * 128 + j;
    unsigned short* y0p =
        y0b + ((size_t)b * Tn + (dir ? Tn - 1 : 0)) * 256 + dir * 128 + j;

    // gx prefetch double-buffer: raw bf16 bits, converted only at use so the
    // compiler's vmcnt wait lands ~8 steps after issue.
    unsigned short bufA[4][8], bufB[4][8];
#pragma unroll
    for (int f = 0; f < 8; ++f) {
        const unsigned short* gp = p0 + f * gstep;
        bufA[0][f] = gp[0];
        bufA[1][f] = gp[128];
        bufA[2][f] = gp[256];
        bufA[3][f] = gp[384];
    }

    __syncthreads();   // once: covers hbuf zero-init

    auto do8 = [&](unsigned short (&useB)[4][8], unsigned short (&ldB)[4][8],
                   int sb) {
#pragma unroll
        for (int f = 0; f < 8; ++f) {
            const int s = sb + f;

            // MFMA phase: gates[n] = h @ W_hh^T (C rows 0,1 used)
            s16x8 ah0 = *ah0p, ah1 = *ah1p, ah2 = *ah2p, ah3 = *ah3p;

            // issue gx prefetch for step s+8 (consumed 8 steps from now);
            // pointer frozen (in-bounds, values unused) once s+8 > Tn-1
            ldB[0][f] = gp_pre[0];
            ldB[1][f] = gp_pre[128];
            ldB[2][f] = gp_pre[256];
            ldB[3][f] = gp_pre[384];
            if (s < Tn - 9) gp_pre += gstep;

            f32x4 acc[8];
#pragma unroll
            for (int nt = 0; nt < 8; ++nt) acc[nt] = f32x4{0.f, 0.f, 0.f, 0.f};
#pragma unroll
            for (int nt = 0; nt < 8; ++nt)
                acc[nt] = __builtin_amdgcn_mfma_f32_16x16x32_bf16(
                    ah0, wh[nt][0], acc[nt], 0, 0, 0);
#pragma unroll
            for (int nt = 0; nt < 8; ++nt)
                acc[nt] = __builtin_amdgcn_mfma_f32_16x16x32_bf16(
                    ah1, wh[nt][1], acc[nt], 0, 0, 0);
#pragma unroll
            for (int nt = 0; nt < 8; ++nt)
                acc[nt] = __builtin_amdgcn_mfma_f32_16x16x32_bf16(
                    ah2, wh[nt][2], acc[nt], 0, 0, 0);
#pragma unroll
            for (int nt = 0; nt < 8; ++nt)
                acc[nt] = __builtin_amdgcn_mfma_f32_16x16x32_bf16(
                    ah3, wh[nt][3], acc[nt], 0, 0, 0);

            // pre-combine gx + bias off the critical tail (overlaps MFMA +
            // barrier; pulls the prefetch vmcnt wait forward too)
            const float pi = b2f(useB[0][f]) + bi;
            const float pf = b2f(useB[1][f]) + bfv;
            const float pg = b2f(useB[2][f]) + bg;
            const float po = b2f(useB[3][f]) + bo;

            if (q == 0) {
#pragma unroll
                for (int nt = 0; nt < 8; ++nt) {
                    gw0[nt * 16] = acc[nt][0];   // C row 0 -> batch b0
                    gw1[nt * 16] = acc[nt][1];   // C row 1 -> batch b0+1
                }
            }
            ldsbar();   // barrier 1: Gs write -> Gs read (LDS only)

            float g_i = gr[0]   + pi;
            float g_f = gr[128] + pf;
            float g_g = gr[256] + pg;
            float g_o = gr[384] + po;
            float iv = sigm(g_i), fv = sigm(g_f), ov = sigm(g_o);
            float gv = tanh_f(g_g);
            c = fv * c + iv * gv;
            float h = ov * tanh_f(c);
            hlast = h;
            unsigned int hp;
            asm("v_cvt_pk_bf16_f32 %0, %1, %2" : "=v"(hp) : "v"(h), "v"(h));
            unsigned short hb = (unsigned short)hp;
            *hw = hb;
            if (LAYER == 0) *y0p = hb;          // fire-and-forget
            else            *yp  = h;
            yp += ystep; y0p += ystep;

            ldsbar();   // barrier 2: hbuf write -> next step's A-frag read
        }
    };

    for (int sb = 0; sb < Tn; sb += 16) {
        do8(bufA, bufB, sb);
        do8(bufB, bufA, sb + 8);
    }

    const int slot = LAYER * 2 + dir;
    hn[((size_t)slot * Bn + b) * Hn + j] = hlast;
    cn[((size_t)slot * Bn + b) * Hn + j] = c;
}

// ---------------------------------------------------------------------------
extern "C" void kernel_launch(void* const* d_in, const int* in_sizes, int n_in,
                              void* d_out, int out_size, void* d_ws, size_t ws_size,
                              hipStream_t stream)
{
    const float* x     = (const float*)d_in[0];
    const float* wih0f = (const float*)d_in[1];
    const float* whh0f = (const float*)d_in[2];
    const float* b0f   = (const float*)d_in[3];
    const float* wih0b = (const float*)d_in[4];
    const float* whh0b = (const float*)d_in[5];
    const float* b0b   = (const float*)d_in[6];
    const float* wih1f = (const float*)d_in[7];
    const float* whh1f = (const float*)d_in[8];
    const float* b1f   = (const float*)d_in[9];
    const float* wih1b = (const float*)d_in[10];
    const float* whh1b = (const float*)d_in[11];
    const float* b1b   = (const float*)d_in[12];

    float* y  = (float*)d_out;                       // [B][T][256] fp32 (final)
    float* hn = y + (size_t)Mn * 256;                // [4][B][128]
    float* cn = hn + (size_t)4 * Bn * Hn;            // [4][B][128]
    unsigned short* gx = (unsigned short*)d_ws;      // [2][M][512] bf16 = 256 MiB

    unsigned short* scr  = (unsigned short*)d_out;
    unsigned short* y0b  = scr;                              // [M][256] bf16
    unsigned short* xb   = scr + (size_t)Mn * 256;           // [M][32]
    unsigned short* w0bf = xb  + (size_t)Mn * 32;            // [2][512][32]
    unsigned short* w1bf = w0bf + 2 * 512 * 32;              // [2][512][256]

    prep<<<2048, 256, 0, stream>>>(x, wih0f, wih0b, wih1f, wih1b, xb, w0bf, w1bf);

    dim3 gg(1024, 8), gb(256);
    dim3 rg(128, 2), rb(256);

    gemm_tile<32, 1><<<gg, gb, 0, stream>>>(xb, 32, w0bf, gx);
    lstm_rec<0><<<rg, rb, 0, stream>>>(gx, whh0f, whh0b, b0f, b0b, y, y0b, hn, cn);
    gemm_tile<128, 2><<<gg, gb, 0, stream>>>(y0b, 256, w1bf, gx);
    lstm_rec<1><<<rg, rb, 0, stream>>>(gx, whh1f, whh1b, b1f, b1b, y, y0b, hn, cn);
}